// Round 13
// baseline (196.762 us; speedup 1.0000x reference)
//
#include <hip/hip_runtime.h>
#include <hip/hip_bf16.h>

// Problem constants
#define N_ 64
#define C_ 64
#define T_ 300
#define V_ 25
#define K_ 3
#define TT 6              // t-values per tile
#define NTILE 50          // T_/TT
#define NBLK 3200         // total tiles = N_ * NTILE
#define NPERS 1024        // persistent blocks; block bid owns tiles bid + i*NPERS
#define XROW 192          // xs row pitch in elems: TT*32
#define XBUF (64 * XROW)  // one xs buffer (24KB)
#define WP 72             // W-lds row pitch (144B, 16B-aligned b128 frag reads)
#define ATP 40            // At-lds row pitch (80B, 16B-aligned b128 frag reads)
#define NTHR 512          // 8 waves: (ob 0..3) x (t-half 0..1)
#define EPS_ 1e-5f

typedef __bf16 bf16_t;
typedef __bf16 bf16x4 __attribute__((ext_vector_type(4)));
typedef __bf16 bf16x8 __attribute__((ext_vector_type(8)));
typedef float f32x4 __attribute__((ext_vector_type(4)));
typedef float f32x4u __attribute__((ext_vector_type(4), aligned(4)));

static __device__ __forceinline__ bf16_t tobf(float f) { return (bf16_t)f; }
// element-index swizzle within a c-row (XOR of bits 3..5: keeps 4-runs contiguous)
static __device__ __forceinline__ int emask(int c) { return ((c & 3) << 3) | ((c & 8) << 2); }

// LDS overlay: W/A staging (prologue only; frags move to registers) reuses the
// double-buffered xs region. union = max(35.3KB, 48KB) = 48KB -> 3 blocks/CU.
union SmemU {
  struct { bf16_t W[3 * 64 * WP]; bf16_t At[3 * 32 * ATP]; } wa;
  bf16_t xs[2 * XBUF];
};

struct Frags {
  bf16x8 wfrag[6];
  bf16x8 afrag[3][2];
  int fK[4], fS5[4];
  float bs[4];
  int obase;
};

// ---- coalesced W/A global->LDS staging (bf16)
static __device__ __forceinline__ void stage_wa(
    const float* __restrict__ A, const float* __restrict__ W, SmemU& sm, int tid) {
  for (int m = tid; m < 3072; m += NTHR) {
    f32x4 v4 = *(reinterpret_cast<const f32x4*>(W) + m);
    int f = m << 2;
    int k = f >> 12, o = (f >> 6) & 63, c = f & 63;
    bf16x4 h;
    h[0] = tobf(v4[0]); h[1] = tobf(v4[1]); h[2] = tobf(v4[2]); h[3] = tobf(v4[3]);
    *reinterpret_cast<bf16x4*>(&sm.wa.W[(k * 64 + o) * WP + c]) = h;
  }
  for (int i = tid; i < 3072; i += NTHR) {
    int k = i >> 10, r = i & 1023, w = r >> 5, v = r & 31;
    float val = (v < V_ && w < V_) ? A[k * 625 + v * 25 + w] : 0.f;
    sm.wa.At[(k * 32 + w) * ATP + v] = tobf(val);
  }
}

static __device__ __forceinline__ void read_frags(
    const SmemU& sm, const float* __restrict__ b, int ob, int l15, int lg, Frags& F) {
  const int o = ob * 16 + l15;
  #pragma unroll
  for (int k = 0; k < 3; ++k)
    #pragma unroll
    for (int ch = 0; ch < 2; ++ch)
      F.wfrag[k * 2 + ch] =
          *reinterpret_cast<const bf16x8*>(&sm.wa.W[(k * 64 + o) * WP + ch * 32 + lg * 8]);
  #pragma unroll
  for (int k = 0; k < 3; ++k)
    #pragma unroll
    for (int wh = 0; wh < 2; ++wh)
      F.afrag[k][wh] =
          *reinterpret_cast<const bf16x8*>(&sm.wa.At[(k * 32 + wh * 16 + l15) * ATP + lg * 8]);
  // per-lane fragment LDS offsets. Permuted c-map (R3..R12-verified):
  // frag q=(chalf,sub): c = chalf*32 + sub*4 + 8*(l15>>2) + (l15&3)
  const int crow = 8 * (l15 >> 2) + (l15 & 3);
  #pragma unroll
  for (int q = 0; q < 4; ++q) {
    int c = ((q >> 1) * 32) + ((q & 1) * 4) + crow;
    int em = emask(c);
    F.fK[q] = c * XROW + ((lg * 8) ^ (em & 24));
    F.fS5[q] = em & 32;
  }
  F.obase = ob * 16 + lg * 4;
  #pragma unroll
  for (int r = 0; r < 4; ++r)
    F.bs[r] = b[F.obase + r] + b[64 + F.obase + r] + b[128 + F.obase + r];
}

// ---- prefetch issue: per-thread (c = tid>>3, vb = tid&7) global loads -> regs.
// No waitcnt here; compiler inserts the wait at first use (stage_write).
static __device__ __forceinline__ void prefetch_issue(
    f32x4u* pv, const float* __restrict__ x, int tile, int c, int vb) {
  const int n = tile / NTILE;
  const int t0 = (tile - n * NTILE) * TT;
  const float* xr = x + (size_t)n * 480000 + (size_t)c * 7500 + (size_t)t0 * 25;
  if (vb < 6) {
    #pragma unroll
    for (int t = 0; t < TT; ++t)
      pv[t] = *reinterpret_cast<const f32x4u*>(xr + t * 25 + vb * 4);
  } else if (vb == 6) {
    #pragma unroll
    for (int t = 0; t < TT; ++t)
      pv[t][0] = xr[t * 25 + 24];
  }
}

// ---- write prefetched regs -> LDS buffer (bf16, swizzled). Pads zeroed.
static __device__ __forceinline__ void stage_write(
    const f32x4u* pv, bf16_t* xsbuf, int c, int vb, int em) {
  bf16_t* xsr = xsbuf + c * XROW;
  #pragma unroll
  for (int t = 0; t < TT; ++t) {
    bf16x4 h;
    if (vb < 6) {
      h[0] = tobf(pv[t][0]); h[1] = tobf(pv[t][1]);
      h[2] = tobf(pv[t][2]); h[3] = tobf(pv[t][3]);
    } else if (vb == 6) {
      h[0] = tobf(pv[t][0]); h[1] = tobf(0.f); h[2] = tobf(0.f); h[3] = tobf(0.f);
    } else {
      h[0] = tobf(0.f); h[1] = tobf(0.f); h[2] = tobf(0.f); h[3] = tobf(0.f);
    }
    *reinterpret_cast<bf16x4*>(&xsr[(((t << 5) + vb * 4) ^ em)]) = h;
  }
}

// one t, one wh: register-chained stage-A -> stage-B (R3..R12-verified mapping)
static __device__ __forceinline__ void compute_wh(
    const bf16x8* xf, const Frags& F, int wh, f32x4& acc0, f32x4& acc1) {
  acc0 = f32x4{0.f, 0.f, 0.f, 0.f};
  acc1 = f32x4{0.f, 0.f, 0.f, 0.f};
  #pragma unroll
  for (int k = 0; k < 3; ++k) {
    #pragma unroll
    for (int ch = 0; ch < 2; ++ch) {
      f32x4 zero = {0.f, 0.f, 0.f, 0.f};
      f32x4 dP = __builtin_amdgcn_mfma_f32_16x16x32_bf16(xf[ch * 2 + 0], F.afrag[k][wh], zero, 0, 0, 0);
      f32x4 dQ = __builtin_amdgcn_mfma_f32_16x16x32_bf16(xf[ch * 2 + 1], F.afrag[k][wh], zero, 0, 0, 0);
      bf16x8 zf;
      zf[0] = tobf(dP[0]); zf[1] = tobf(dP[1]); zf[2] = tobf(dP[2]); zf[3] = tobf(dP[3]);
      zf[4] = tobf(dQ[0]); zf[5] = tobf(dQ[1]); zf[6] = tobf(dQ[2]); zf[7] = tobf(dQ[3]);
      if (ch == 0)
        acc0 = __builtin_amdgcn_mfma_f32_16x16x32_bf16(F.wfrag[k * 2 + ch], zf, acc0, 0, 0, 0);
      else
        acc1 = __builtin_amdgcn_mfma_f32_16x16x32_bf16(F.wfrag[k * 2 + ch], zf, acc1, 0, 0, 0);
    }
  }
}

// ---------------------------------------------------------------------------
// K1: persistent static schedule + double-buffered xs + register prefetch.
// Per tile: {issue next loads} -> compute cur buffer -> {write next buffer}
// -> ONE barrier. Stats accumulate in registers across tiles; one part
// write per block.
// ---------------------------------------------------------------------------
__global__ __launch_bounds__(NTHR, 4) void k1_compute(
    const float* __restrict__ x, const float* __restrict__ A,
    const float* __restrict__ W, const float* __restrict__ b,
    float* __restrict__ y, float* __restrict__ part) {
  __shared__ __align__(16) SmemU sm;
  __shared__ float stats2[2][2][64];   // [sum|sq][t-half][o]

  const int bid = blockIdx.x;
  const int tid = threadIdx.x;
  const int lane = tid & 63;
  const int wv = tid >> 6;        // 0..7
  const int ob = wv & 3;          // o-block
  const int th = wv >> 2;         // t-half
  const int l15 = lane & 15;
  const int lg = lane >> 4;
  const int c = tid >> 3, vb = tid & 7;
  const int em = emask(c);

  stage_wa(A, W, sm, tid);
  __syncthreads();
  Frags F;
  read_frags(sm, b, ob, l15, lg, F);
  __syncthreads();                 // all wa reads done before xs overwrite

  const int nt = (bid < (NBLK - 3 * NPERS)) ? 4 : 3;   // 128 blocks get 4 tiles
  const int w_lo = l15, w_hi = 16 + l15;

  float lsum[4] = {0.f, 0.f, 0.f, 0.f}, lsq[4] = {0.f, 0.f, 0.f, 0.f};
  f32x4u pv[TT];

  // preload tile 0 into buf 0
  prefetch_issue(pv, x, bid, c, vb);
  stage_write(pv, sm.xs, c, vb, em);
  __syncthreads();

  int cur = 0;
  for (int i = 0; i < nt; ++i) {
    const int tile = bid + i * NPERS;
    const int n = tile / NTILE;
    const int t0 = (tile - n * NTILE) * TT;

    if (i + 1 < nt) prefetch_issue(pv, x, tile + NPERS, c, vb);

    const bf16_t* xsc = sm.xs + cur * XBUF;
    float* yb = y + (size_t)n * 480000 + (size_t)t0 * 25;

    #pragma unroll
    for (int tl = 0; tl < 3; ++tl) {
      const int t = th * 3 + tl;
      bf16x8 xf[4];
      #pragma unroll
      for (int q = 0; q < 4; ++q)
        xf[q] = *reinterpret_cast<const bf16x8*>(xsc + F.fK[q] + ((t << 5) ^ F.fS5[q]));
      #pragma unroll
      for (int wh = 0; wh < 2; ++wh) {
        f32x4 acc0, acc1;
        compute_wh(xf, F, wh, acc0, acc1);
        const int w = wh ? w_hi : w_lo;
        if (w < V_) {
          #pragma unroll
          for (int r = 0; r < 4; ++r) {
            float val = acc0[r] + acc1[r] + F.bs[r];
            lsum[r] += val;
            lsq[r] += val * val;
            yb[(size_t)(F.obase + r) * 7500 + t * 25 + w] = val;
          }
        }
      }
    }

    if (i + 1 < nt) stage_write(pv, sm.xs + (cur ^ 1) * XBUF, c, vb, em);
    __syncthreads();   // next buffer ready; everyone done reading cur
    cur ^= 1;
  }

  // one epilogue per block: reduce across the 16 lanes sharing the 4 o-rows
  #pragma unroll
  for (int d = 1; d < 16; d <<= 1) {
    #pragma unroll
    for (int r = 0; r < 4; ++r) {
      lsum[r] += __shfl_xor(lsum[r], d);
      lsq[r]  += __shfl_xor(lsq[r], d);
    }
  }
  if (l15 == 0) {
    #pragma unroll
    for (int r = 0; r < 4; ++r) {
      stats2[0][th][F.obase + r] = lsum[r];
      stats2[1][th][F.obase + r] = lsq[r];
    }
  }
  __syncthreads();
  if (tid < 128)
    part[(size_t)bid * 128 + tid] =
        stats2[tid >> 6][0][tid & 63] + stats2[tid >> 6][1][tid & 63];
}

// ---------------------------------------------------------------------------
// K2: reduce per-block partials (NPERS entries) -> per-channel scale/shift
// ---------------------------------------------------------------------------
__global__ __launch_bounds__(256) void k2_stats(
    const float* __restrict__ part,
    const float* __restrict__ gamma, const float* __restrict__ beta,
    float* __restrict__ ss) {
  const int o = blockIdx.x;
  const int tid = threadIdx.x;
  double s = 0.0, q = 0.0;
  for (int i = tid; i < NPERS; i += 256) {
    s += (double)part[(size_t)i * 128 + o];
    q += (double)part[(size_t)i * 128 + 64 + o];
  }
  __shared__ double sd[256], qd[256];
  sd[tid] = s; qd[tid] = q;
  __syncthreads();
  for (int step = 128; step > 0; step >>= 1) {
    if (tid < step) { sd[tid] += sd[tid + step]; qd[tid] += qd[tid + step]; }
    __syncthreads();
  }
  if (tid == 0) {
    const double cnt = 480000.0;
    double mean = sd[0] / cnt;
    double var = qd[0] / cnt - mean * mean;
    float inv = rsqrtf((float)var + EPS_);
    float sc = gamma[o] * inv;
    float sh = beta[o] - (float)mean * sc;
    ss[2 * o] = sc;
    ss[2 * o + 1] = sh;
  }
}

// ---------------------------------------------------------------------------
// K3: out = relu(scale[c]*y + shift[c] + x), in place on d_out (y staged there).
// ---------------------------------------------------------------------------
__global__ __launch_bounds__(256) void k3_finish(
    const float* __restrict__ x, const float* __restrict__ ss,
    float* __restrict__ y) {
  const int p = blockIdx.x;       // 0..4095 = n*64 + c
  const int c = p & 63;
  const float sc = ss[2 * c];
  const float sh = ss[2 * c + 1];
  const float4* xv = reinterpret_cast<const float4*>(x + (size_t)p * 7500);
  float4* yv = reinterpret_cast<float4*>(y + (size_t)p * 7500);
  for (int i = threadIdx.x; i < 1875; i += 256) {
    float4 a = yv[i];
    float4 b4 = xv[i];
    float4 o;
    o.x = fmaxf(sc * a.x + sh + b4.x, 0.f);
    o.y = fmaxf(sc * a.y + sh + b4.y, 0.f);
    o.z = fmaxf(sc * a.z + sh + b4.z, 0.f);
    o.w = fmaxf(sc * a.w + sh + b4.w, 0.f);
    yv[i] = o;
  }
}

extern "C" void kernel_launch(void* const* d_in, const int* in_sizes, int n_in,
                              void* d_out, int out_size, void* d_ws, size_t ws_size,
                              hipStream_t stream) {
  const float* x     = (const float*)d_in[0];
  const float* A     = (const float*)d_in[1];
  const float* W     = (const float*)d_in[2];
  const float* b     = (const float*)d_in[3];
  const float* gamma = (const float*)d_in[4];
  const float* beta  = (const float*)d_in[5];
  float* y = (float*)d_out;                  // stage y in d_out, finish in place

  float* part = (float*)d_ws;                // NPERS*128 floats (contiguous per block)
  float* ss   = part + (size_t)NPERS * 128;  // 128 floats

  k1_compute<<<NPERS, NTHR, 0, stream>>>(x, A, W, b, y, part);
  k2_stats<<<64, 256, 0, stream>>>(part, gamma, beta, ss);
  k3_finish<<<4096, 256, 0, stream>>>(x, ss, y);
}

// Round 14
// 169.763 us; speedup vs baseline: 1.1590x; 1.1590x over previous
//
#include <hip/hip_runtime.h>
#include <hip/hip_bf16.h>

// Problem constants
#define N_ 64
#define C_ 64
#define T_ 300
#define V_ 25
#define K_ 3
#define TT 12             // t-values per tile
#define NTILE 25          // T_/TT
#define NBLK 1600         // total tiles
#define NPERS 800         // blocks; block bid owns tiles 2*bid, 2*bid+1
#define XROW 384          // xs row pitch in elems: TT*32
#define WP 72             // W-lds row pitch (144B, 16B-aligned b128 frag reads)
#define ATP 40            // At-lds row pitch (80B, 16B-aligned b128 frag reads)
#define NTHR 512          // 8 waves: (ob 0..3) x (t-half 0..1)
#define EPS_ 1e-5f

typedef __bf16 bf16_t;
typedef __bf16 bf16x4 __attribute__((ext_vector_type(4)));
typedef __bf16 bf16x8 __attribute__((ext_vector_type(8)));
typedef float f32x4 __attribute__((ext_vector_type(4)));
typedef float f32x4u __attribute__((ext_vector_type(4), aligned(4)));

static __device__ __forceinline__ bf16_t tobf(float f) { return (bf16_t)f; }
// element-index swizzle within a c-row (XOR of bits 3..5: keeps 4-runs contiguous)
static __device__ __forceinline__ int emask(int c) { return ((c & 3) << 3) | ((c & 8) << 2); }

// LDS overlay: W/A staging (prologue only; frags move to registers) reuses xs.
union SmemU {
  struct { bf16_t W[3 * 64 * WP]; bf16_t At[3 * 32 * ATP]; } wa;   // 35.3KB
  bf16_t xs[64 * XROW];                                            // 48KB
};

struct Frags {
  bf16x8 wfrag[6];
  bf16x8 afrag[3][2];
  int fK[4], fS5[4];
  float bs[4];
  int obase;
};

// ---- coalesced W/A global->LDS staging (bf16)
static __device__ __forceinline__ void stage_wa(
    const float* __restrict__ A, const float* __restrict__ W, SmemU& sm, int tid) {
  for (int m = tid; m < 3072; m += NTHR) {
    f32x4 v4 = *(reinterpret_cast<const f32x4*>(W) + m);
    int f = m << 2;
    int k = f >> 12, o = (f >> 6) & 63, c = f & 63;
    bf16x4 h;
    h[0] = tobf(v4[0]); h[1] = tobf(v4[1]); h[2] = tobf(v4[2]); h[3] = tobf(v4[3]);
    *reinterpret_cast<bf16x4*>(&sm.wa.W[(k * 64 + o) * WP + c]) = h;
  }
  for (int i = tid; i < 3072; i += NTHR) {
    int k = i >> 10, r = i & 1023, w = r >> 5, v = r & 31;
    float val = (v < V_ && w < V_) ? A[k * 625 + v * 25 + w] : 0.f;
    sm.wa.At[(k * 32 + w) * ATP + v] = tobf(val);
  }
}

static __device__ __forceinline__ void read_frags(
    const SmemU& sm, const float* __restrict__ b, int ob, int l15, int lg, Frags& F) {
  const int o = ob * 16 + l15;
  #pragma unroll
  for (int k = 0; k < 3; ++k)
    #pragma unroll
    for (int ch = 0; ch < 2; ++ch)
      F.wfrag[k * 2 + ch] =
          *reinterpret_cast<const bf16x8*>(&sm.wa.W[(k * 64 + o) * WP + ch * 32 + lg * 8]);
  #pragma unroll
  for (int k = 0; k < 3; ++k)
    #pragma unroll
    for (int wh = 0; wh < 2; ++wh)
      F.afrag[k][wh] =
          *reinterpret_cast<const bf16x8*>(&sm.wa.At[(k * 32 + wh * 16 + l15) * ATP + lg * 8]);
  // per-lane fragment LDS offsets. Permuted c-map (R3..R12-verified):
  // frag q=(chalf,sub): c = chalf*32 + sub*4 + 8*(l15>>2) + (l15&3)
  const int crow = 8 * (l15 >> 2) + (l15 & 3);
  #pragma unroll
  for (int q = 0; q < 4; ++q) {
    int c = ((q >> 1) * 32) + ((q & 1) * 4) + crow;
    int em = emask(c);
    F.fK[q] = c * XROW + ((lg * 8) ^ (em & 24));
    F.fS5[q] = em & 32;
  }
  F.obase = ob * 16 + lg * 4;
  #pragma unroll
  for (int r = 0; r < 4; ++r)
    F.bs[r] = b[F.obase + r] + b[64 + F.obase + r] + b[128 + F.obase + r];
}

// ---- prestream: pull this block's 2 tiles HBM->L3 at full BW (no barriers,
// high MLP, asm-sunk so DCE can't delete the loads -- rule #17).
static __device__ __forceinline__ void prestream2(
    const float* __restrict__ x, int bid, int tid) {
  float sink = 0.f;
  const int c = tid >> 3, q = tid & 7;
  #pragma unroll
  for (int i = 0; i < 2; ++i) {
    const int tile = bid * 2 + i;
    const int n = tile / NTILE;
    const int t0 = (tile - n * NTILE) * TT;
    const float* tb = x + (size_t)n * 480000 + (size_t)c * 7500 + (size_t)t0 * 25;
    for (int j = q; j < 75; j += 8) {        // 75 float4 per c-row, 16B-aligned
      f32x4 v = *reinterpret_cast<const f32x4*>(tb + 4 * j);
      sink += v[0] + v[1] + v[2] + v[3];
    }
  }
  asm volatile("" :: "v"(sink));
}

// ---- x staging: 512 threads = 64 c-rows x 8 v-blocks; pure bit-op indexing.
static __device__ __forceinline__ void stage_x(
    const float* __restrict__ x, SmemU& sm, int n, int t0, int tid) {
  const int c = tid >> 3, vb = tid & 7;
  const int em = emask(c);
  const float* xr = x + (size_t)n * 480000 + (size_t)c * 7500 + (size_t)t0 * 25;
  bf16_t* xsr = &sm.xs[c * XROW];
  #pragma unroll
  for (int t = 0; t < TT; ++t) {
    bf16x4 h;
    if (vb < 6) {
      f32x4u v4 = *reinterpret_cast<const f32x4u*>(xr + t * 25 + vb * 4);
      h[0] = tobf(v4[0]); h[1] = tobf(v4[1]); h[2] = tobf(v4[2]); h[3] = tobf(v4[3]);
    } else if (vb == 6) {
      float s = xr[t * 25 + 24];
      h[0] = tobf(s); h[1] = tobf(0.f); h[2] = tobf(0.f); h[3] = tobf(0.f);
    } else {
      h[0] = tobf(0.f); h[1] = tobf(0.f); h[2] = tobf(0.f); h[3] = tobf(0.f);
    }
    *reinterpret_cast<bf16x4*>(&xsr[(((t << 5) + vb * 4) ^ em)]) = h;
  }
}

// one t, one wh: register-chained stage-A -> stage-B (R3..R12-verified mapping)
static __device__ __forceinline__ void compute_wh(
    const bf16x8* xf, const Frags& F, int wh, f32x4& acc0, f32x4& acc1) {
  acc0 = f32x4{0.f, 0.f, 0.f, 0.f};
  acc1 = f32x4{0.f, 0.f, 0.f, 0.f};
  #pragma unroll
  for (int k = 0; k < 3; ++k) {
    #pragma unroll
    for (int ch = 0; ch < 2; ++ch) {
      f32x4 zero = {0.f, 0.f, 0.f, 0.f};
      f32x4 dP = __builtin_amdgcn_mfma_f32_16x16x32_bf16(xf[ch * 2 + 0], F.afrag[k][wh], zero, 0, 0, 0);
      f32x4 dQ = __builtin_amdgcn_mfma_f32_16x16x32_bf16(xf[ch * 2 + 1], F.afrag[k][wh], zero, 0, 0, 0);
      bf16x8 zf;
      zf[0] = tobf(dP[0]); zf[1] = tobf(dP[1]); zf[2] = tobf(dP[2]); zf[3] = tobf(dP[3]);
      zf[4] = tobf(dQ[0]); zf[5] = tobf(dQ[1]); zf[6] = tobf(dQ[2]); zf[7] = tobf(dQ[3]);
      if (ch == 0)
        acc0 = __builtin_amdgcn_mfma_f32_16x16x32_bf16(F.wfrag[k * 2 + ch], zf, acc0, 0, 0, 0);
      else
        acc1 = __builtin_amdgcn_mfma_f32_16x16x32_bf16(F.wfrag[k * 2 + ch], zf, acc1, 0, 0, 0);
    }
  }
}

// ---------------------------------------------------------------------------
// K1: stats-only (NO y store). Prestream x HBM->L3 (barrier-free), then the
// barriered tile loop consumes it L3-warm. Stats accumulate in registers
// across both tiles; one part write per block.
// ---------------------------------------------------------------------------
__global__ __launch_bounds__(NTHR, 4) void k1_stats(
    const float* __restrict__ x, const float* __restrict__ A,
    const float* __restrict__ W, const float* __restrict__ b,
    float* __restrict__ part) {
  __shared__ __align__(16) SmemU sm;
  __shared__ float stats2[2][2][64];   // [sum|sq][t-half][o]

  const int bid = blockIdx.x;
  const int tid = threadIdx.x;
  const int lane = tid & 63;
  const int wv = tid >> 6;
  const int ob = wv & 3;
  const int th = wv >> 2;
  const int l15 = lane & 15;
  const int lg = lane >> 4;

  stage_wa(A, W, sm, tid);
  prestream2(x, bid, tid);         // overlaps with W/A staging waits
  __syncthreads();
  Frags F;
  read_frags(sm, b, ob, l15, lg, F);
  __syncthreads();                 // all wa reads done before xs overwrite

  float lsum[4] = {0.f, 0.f, 0.f, 0.f}, lsq[4] = {0.f, 0.f, 0.f, 0.f};

  #pragma unroll
  for (int i = 0; i < 2; ++i) {
    const int tile = bid * 2 + i;
    const int n = tile / NTILE;
    const int t0 = (tile - n * NTILE) * TT;

    stage_x(x, sm, n, t0, tid);
    __syncthreads();

    #pragma unroll 2
    for (int tl = 0; tl < 6; ++tl) {
      const int t = th * 6 + tl;
      bf16x8 xf[4];
      #pragma unroll
      for (int q = 0; q < 4; ++q)
        xf[q] = *reinterpret_cast<const bf16x8*>(sm.xs + F.fK[q] + ((t << 5) ^ F.fS5[q]));
      #pragma unroll
      for (int wh = 0; wh < 2; ++wh) {
        f32x4 acc0, acc1;
        compute_wh(xf, F, wh, acc0, acc1);
        const int w = wh ? 16 + l15 : l15;
        if (w < V_) {
          #pragma unroll
          for (int r = 0; r < 4; ++r) {
            float val = acc0[r] + acc1[r] + F.bs[r];
            lsum[r] += val;
            lsq[r] += val * val;
          }
        }
      }
    }
    __syncthreads();   // all xs reads done before next tile's stage_x
  }

  #pragma unroll
  for (int d = 1; d < 16; d <<= 1) {
    #pragma unroll
    for (int r = 0; r < 4; ++r) {
      lsum[r] += __shfl_xor(lsum[r], d);
      lsq[r]  += __shfl_xor(lsq[r], d);
    }
  }
  if (l15 == 0) {
    #pragma unroll
    for (int r = 0; r < 4; ++r) {
      stats2[0][th][F.obase + r] = lsum[r];
      stats2[1][th][F.obase + r] = lsq[r];
    }
  }
  __syncthreads();
  if (tid < 128)
    part[(size_t)bid * 128 + tid] =
        stats2[tid >> 6][0][tid & 63] + stats2[tid >> 6][1][tid & 63];
}

// ---------------------------------------------------------------------------
// K2: reduce per-block partials -> per-channel scale/shift
// ---------------------------------------------------------------------------
__global__ __launch_bounds__(256) void k2_stats(
    const float* __restrict__ part,
    const float* __restrict__ gamma, const float* __restrict__ beta,
    float* __restrict__ ss) {
  const int o = blockIdx.x;
  const int tid = threadIdx.x;
  double s = 0.0, q = 0.0;
  for (int i = tid; i < NPERS; i += 256) {
    s += (double)part[(size_t)i * 128 + o];
    q += (double)part[(size_t)i * 128 + 64 + o];
  }
  __shared__ double sd[256], qd[256];
  sd[tid] = s; qd[tid] = q;
  __syncthreads();
  for (int step = 128; step > 0; step >>= 1) {
    if (tid < step) { sd[tid] += sd[tid + step]; qd[tid] += qd[tid + step]; }
    __syncthreads();
  }
  if (tid == 0) {
    const double cnt = 480000.0;
    double mean = sd[0] / cnt;
    double var = qd[0] / cnt - mean * mean;
    float inv = rsqrtf((float)var + EPS_);
    float sc = gamma[o] * inv;
    float sh = beta[o] - (float)mean * sc;
    ss[2 * o] = sc;
    ss[2 * o + 1] = sh;
  }
}

// ---------------------------------------------------------------------------
// K3: recompute y (x now L3-warm), apply BN + residual (x from LDS, bf16)
// + relu, store out. Same skeleton as K1.
// ---------------------------------------------------------------------------
__global__ __launch_bounds__(NTHR, 4) void k3_apply(
    const float* __restrict__ x, const float* __restrict__ A,
    const float* __restrict__ W, const float* __restrict__ b,
    const float* __restrict__ ss, float* __restrict__ out) {
  __shared__ __align__(16) SmemU sm;

  const int bid = blockIdx.x;
  const int tid = threadIdx.x;
  const int lane = tid & 63;
  const int wv = tid >> 6;
  const int ob = wv & 3;
  const int th = wv >> 2;
  const int l15 = lane & 15;
  const int lg = lane >> 4;

  stage_wa(A, W, sm, tid);
  __syncthreads();
  Frags F;
  read_frags(sm, b, ob, l15, lg, F);

  float sc[4], sh[4];
  #pragma unroll
  for (int r = 0; r < 4; ++r) {
    sc[r] = ss[2 * (F.obase + r)];
    sh[r] = ss[2 * (F.obase + r) + 1];
  }
  __syncthreads();                 // all wa reads done before xs overwrite

  #pragma unroll
  for (int i = 0; i < 2; ++i) {
    const int tile = bid * 2 + i;
    const int n = tile / NTILE;
    const int t0 = (tile - n * NTILE) * TT;

    stage_x(x, sm, n, t0, tid);
    __syncthreads();

    float* obp = out + (size_t)n * 480000 + (size_t)t0 * 25;

    #pragma unroll 2
    for (int tl = 0; tl < 6; ++tl) {
      const int t = th * 6 + tl;
      bf16x8 xf[4];
      #pragma unroll
      for (int q = 0; q < 4; ++q)
        xf[q] = *reinterpret_cast<const bf16x8*>(sm.xs + F.fK[q] + ((t << 5) ^ F.fS5[q]));
      #pragma unroll
      for (int wh = 0; wh < 2; ++wh) {
        f32x4 acc0, acc1;
        compute_wh(xf, F, wh, acc0, acc1);
        const int w = wh ? 16 + l15 : l15;
        if (w < V_) {
          #pragma unroll
          for (int r = 0; r < 4; ++r) {
            const int o = F.obase + r;
            float val = acc0[r] + acc1[r] + F.bs[r];
            float xr = (float)sm.xs[o * XROW + (((t << 5) + w) ^ emask(o))];
            obp[(size_t)o * 7500 + t * 25 + w] = fmaxf(sc[r] * val + sh[r] + xr, 0.f);
          }
        }
      }
    }
    __syncthreads();   // all xs reads done before next tile's stage_x
  }
}

extern "C" void kernel_launch(void* const* d_in, const int* in_sizes, int n_in,
                              void* d_out, int out_size, void* d_ws, size_t ws_size,
                              hipStream_t stream) {
  const float* x     = (const float*)d_in[0];
  const float* A     = (const float*)d_in[1];
  const float* W     = (const float*)d_in[2];
  const float* b     = (const float*)d_in[3];
  const float* gamma = (const float*)d_in[4];
  const float* beta  = (const float*)d_in[5];
  float* out = (float*)d_out;

  float* part = (float*)d_ws;                // NPERS*128 floats
  float* ss   = part + (size_t)NPERS * 128;  // 128 floats

  k1_stats<<<NPERS, NTHR, 0, stream>>>(x, A, W, b, part);
  k2_stats<<<64, 256, 0, stream>>>(part, gamma, beta, ss);
  k3_apply<<<NPERS, NTHR, 0, stream>>>(x, A, W, b, ss, out);
}

// Round 15
// 154.423 us; speedup vs baseline: 1.2742x; 1.0993x over previous
//
#include <hip/hip_runtime.h>
#include <hip/hip_bf16.h>

// Problem constants
#define N_ 64
#define C_ 64
#define T_ 300
#define V_ 25
#define K_ 3
#define TT 12             // t-values per tile
#define NTILE 25          // T_/TT
#define NBLK 1600         // total tiles
#define NPERS 800         // blocks; block bid owns tiles 2*bid, 2*bid+1
#define XROW 384          // xs row pitch in elems: TT*32
#define WP 72             // W-lds row pitch (144B, 16B-aligned b128 frag reads)
#define ATP 40            // At-lds row pitch (80B, 16B-aligned b128 frag reads)
#define NTHR 512          // 8 waves: (ob 0..3) x (t-half 0..1)
#define EPS_ 1e-5f

typedef __bf16 bf16_t;
typedef __bf16 bf16x4 __attribute__((ext_vector_type(4)));
typedef __bf16 bf16x8 __attribute__((ext_vector_type(8)));
typedef float f32x4 __attribute__((ext_vector_type(4)));
typedef float f32x4u __attribute__((ext_vector_type(4), aligned(4)));

static __device__ __forceinline__ bf16_t tobf(float f) { return (bf16_t)f; }
// element-index swizzle within a c-row (XOR of bits 3..5: keeps 4-runs contiguous)
static __device__ __forceinline__ int emask(int c) { return ((c & 3) << 3) | ((c & 8) << 2); }

// LDS overlay: W/A staging (prologue only; frags move to registers) reuses xs.
union SmemU {
  struct { bf16_t W[3 * 64 * WP]; bf16_t At[3 * 32 * ATP]; } wa;   // 35.3KB
  bf16_t xs[64 * XROW];                                            // 48KB
};

struct Frags {
  bf16x8 wfrag[6];
  bf16x8 afrag[3][2];
  int fK[4], fS5[4];
  float bs[4];
  int obase;
};

// ---- coalesced W/A global->LDS staging (bf16)
static __device__ __forceinline__ void stage_wa(
    const float* __restrict__ A, const float* __restrict__ W, SmemU& sm, int tid) {
  for (int m = tid; m < 3072; m += NTHR) {
    f32x4 v4 = *(reinterpret_cast<const f32x4*>(W) + m);
    int f = m << 2;
    int k = f >> 12, o = (f >> 6) & 63, c = f & 63;
    bf16x4 h;
    h[0] = tobf(v4[0]); h[1] = tobf(v4[1]); h[2] = tobf(v4[2]); h[3] = tobf(v4[3]);
    *reinterpret_cast<bf16x4*>(&sm.wa.W[(k * 64 + o) * WP + c]) = h;
  }
  for (int i = tid; i < 3072; i += NTHR) {
    int k = i >> 10, r = i & 1023, w = r >> 5, v = r & 31;
    float val = (v < V_ && w < V_) ? A[k * 625 + v * 25 + w] : 0.f;
    sm.wa.At[(k * 32 + w) * ATP + v] = tobf(val);
  }
}

static __device__ __forceinline__ void read_frags(
    const SmemU& sm, const float* __restrict__ b, int ob, int l15, int lg, Frags& F) {
  const int o = ob * 16 + l15;
  #pragma unroll
  for (int k = 0; k < 3; ++k)
    #pragma unroll
    for (int ch = 0; ch < 2; ++ch)
      F.wfrag[k * 2 + ch] =
          *reinterpret_cast<const bf16x8*>(&sm.wa.W[(k * 64 + o) * WP + ch * 32 + lg * 8]);
  #pragma unroll
  for (int k = 0; k < 3; ++k)
    #pragma unroll
    for (int wh = 0; wh < 2; ++wh)
      F.afrag[k][wh] =
          *reinterpret_cast<const bf16x8*>(&sm.wa.At[(k * 32 + wh * 16 + l15) * ATP + lg * 8]);
  // per-lane fragment LDS offsets. Permuted c-map (R3..R14-verified):
  // frag q=(chalf,sub): c = chalf*32 + sub*4 + 8*(l15>>2) + (l15&3)
  const int crow = 8 * (l15 >> 2) + (l15 & 3);
  #pragma unroll
  for (int q = 0; q < 4; ++q) {
    int c = ((q >> 1) * 32) + ((q & 1) * 4) + crow;
    int em = emask(c);
    F.fK[q] = c * XROW + ((lg * 8) ^ (em & 24));
    F.fS5[q] = em & 32;
  }
  F.obase = ob * 16 + lg * 4;
  #pragma unroll
  for (int r = 0; r < 4; ++r)
    F.bs[r] = b[F.obase + r] + b[64 + F.obase + r] + b[128 + F.obase + r];
}

// ---- overlapped touch: issue 3 line-strided loads of a FUTURE tile's x.
// Their only use (sink add) is placed AFTER the compute loop, so the HBM
// latency hides under MFMA work. 1536 touches >= 1216 lines per tile.
static __device__ __forceinline__ void touch_issue(
    const float* __restrict__ x, int tile, int tid, float* tv) {
  const int n = tile / NTILE;
  const int t0 = (tile - n * NTILE) * TT;
  const float* base = x + (size_t)n * 480000 + (size_t)t0 * 25;
  #pragma unroll
  for (int j = 0; j < 3; ++j) {
    int idx = tid + (j << 9);          // 0..1535
    int c = idx / 19;                  // 19 lines (64B) per c-row
    int li = idx - c * 19;
    tv[j] = (c < 64) ? base[(size_t)c * 7500 + li * 16] : 0.f;
  }
}

// ---- x staging: 512 threads = 64 c-rows x 8 v-blocks; pure bit-op indexing.
static __device__ __forceinline__ void stage_x(
    const float* __restrict__ x, SmemU& sm, int n, int t0, int tid) {
  const int c = tid >> 3, vb = tid & 7;
  const int em = emask(c);
  const float* xr = x + (size_t)n * 480000 + (size_t)c * 7500 + (size_t)t0 * 25;
  bf16_t* xsr = &sm.xs[c * XROW];
  #pragma unroll
  for (int t = 0; t < TT; ++t) {
    bf16x4 h;
    if (vb < 6) {
      f32x4u v4 = *reinterpret_cast<const f32x4u*>(xr + t * 25 + vb * 4);
      h[0] = tobf(v4[0]); h[1] = tobf(v4[1]); h[2] = tobf(v4[2]); h[3] = tobf(v4[3]);
    } else if (vb == 6) {
      float s = xr[t * 25 + 24];
      h[0] = tobf(s); h[1] = tobf(0.f); h[2] = tobf(0.f); h[3] = tobf(0.f);
    } else {
      h[0] = tobf(0.f); h[1] = tobf(0.f); h[2] = tobf(0.f); h[3] = tobf(0.f);
    }
    *reinterpret_cast<bf16x4*>(&xsr[(((t << 5) + vb * 4) ^ em)]) = h;
  }
}

// one t, one wh: register-chained stage-A -> stage-B (R3..R14-verified mapping)
static __device__ __forceinline__ void compute_wh(
    const bf16x8* xf, const Frags& F, int wh, f32x4& acc0, f32x4& acc1) {
  acc0 = f32x4{0.f, 0.f, 0.f, 0.f};
  acc1 = f32x4{0.f, 0.f, 0.f, 0.f};
  #pragma unroll
  for (int k = 0; k < 3; ++k) {
    #pragma unroll
    for (int ch = 0; ch < 2; ++ch) {
      f32x4 zero = {0.f, 0.f, 0.f, 0.f};
      f32x4 dP = __builtin_amdgcn_mfma_f32_16x16x32_bf16(xf[ch * 2 + 0], F.afrag[k][wh], zero, 0, 0, 0);
      f32x4 dQ = __builtin_amdgcn_mfma_f32_16x16x32_bf16(xf[ch * 2 + 1], F.afrag[k][wh], zero, 0, 0, 0);
      bf16x8 zf;
      zf[0] = tobf(dP[0]); zf[1] = tobf(dP[1]); zf[2] = tobf(dP[2]); zf[3] = tobf(dP[3]);
      zf[4] = tobf(dQ[0]); zf[5] = tobf(dQ[1]); zf[6] = tobf(dQ[2]); zf[7] = tobf(dQ[3]);
      if (ch == 0)
        acc0 = __builtin_amdgcn_mfma_f32_16x16x32_bf16(F.wfrag[k * 2 + ch], zf, acc0, 0, 0, 0);
      else
        acc1 = __builtin_amdgcn_mfma_f32_16x16x32_bf16(F.wfrag[k * 2 + ch], zf, acc1, 0, 0, 0);
    }
  }
}

// ---------------------------------------------------------------------------
// K1: stats-only (NO y store). While tile 0 computes, tile 1's cache lines
// are pulled by overlapped touch loads (sink consumed after compute).
// ---------------------------------------------------------------------------
__global__ __launch_bounds__(NTHR, 4) void k1_stats(
    const float* __restrict__ x, const float* __restrict__ A,
    const float* __restrict__ W, const float* __restrict__ b,
    float* __restrict__ part) {
  __shared__ __align__(16) SmemU sm;
  __shared__ float stats2[2][2][64];   // [sum|sq][t-half][o]

  const int bid = blockIdx.x;
  const int tid = threadIdx.x;
  const int lane = tid & 63;
  const int wv = tid >> 6;
  const int ob = wv & 3;
  const int th = wv >> 2;
  const int l15 = lane & 15;
  const int lg = lane >> 4;

  stage_wa(A, W, sm, tid);
  __syncthreads();
  Frags F;
  read_frags(sm, b, ob, l15, lg, F);
  __syncthreads();                 // all wa reads done before xs overwrite

  float lsum[4] = {0.f, 0.f, 0.f, 0.f}, lsq[4] = {0.f, 0.f, 0.f, 0.f};
  float sink = 0.f;

  #pragma unroll
  for (int i = 0; i < 2; ++i) {
    const int tile = bid * 2 + i;
    const int n = tile / NTILE;
    const int t0 = (tile - n * NTILE) * TT;

    stage_x(x, sm, n, t0, tid);
    __syncthreads();

    float tv[3] = {0.f, 0.f, 0.f};
    if (i == 0) touch_issue(x, tile + 1, tid, tv);   // overlaps the compute below

    #pragma unroll 2
    for (int tl = 0; tl < 6; ++tl) {
      const int t = th * 6 + tl;
      bf16x8 xf[4];
      #pragma unroll
      for (int q = 0; q < 4; ++q)
        xf[q] = *reinterpret_cast<const bf16x8*>(sm.xs + F.fK[q] + ((t << 5) ^ F.fS5[q]));
      #pragma unroll
      for (int wh = 0; wh < 2; ++wh) {
        f32x4 acc0, acc1;
        compute_wh(xf, F, wh, acc0, acc1);
        const int w = wh ? 16 + l15 : l15;
        if (w < V_) {
          #pragma unroll
          for (int r = 0; r < 4; ++r) {
            float val = acc0[r] + acc1[r] + F.bs[r];
            lsum[r] += val;
            lsq[r] += val * val;
          }
        }
      }
    }
    sink += tv[0] + tv[1] + tv[2];   // touch consumption AFTER compute
    __syncthreads();   // all xs reads done before next tile's stage_x
  }
  asm volatile("" :: "v"(sink));     // keep touches alive (rule #17)

  #pragma unroll
  for (int d = 1; d < 16; d <<= 1) {
    #pragma unroll
    for (int r = 0; r < 4; ++r) {
      lsum[r] += __shfl_xor(lsum[r], d);
      lsq[r]  += __shfl_xor(lsq[r], d);
    }
  }
  if (l15 == 0) {
    #pragma unroll
    for (int r = 0; r < 4; ++r) {
      stats2[0][th][F.obase + r] = lsum[r];
      stats2[1][th][F.obase + r] = lsq[r];
    }
  }
  __syncthreads();
  if (tid < 128)
    part[(size_t)bid * 128 + tid] =
        stats2[tid >> 6][0][tid & 63] + stats2[tid >> 6][1][tid & 63];
}

// ---------------------------------------------------------------------------
// K2: reduce per-block partials -> per-channel scale/shift
// ---------------------------------------------------------------------------
__global__ __launch_bounds__(256) void k2_stats(
    const float* __restrict__ part,
    const float* __restrict__ gamma, const float* __restrict__ beta,
    float* __restrict__ ss) {
  const int o = blockIdx.x;
  const int tid = threadIdx.x;
  double s = 0.0, q = 0.0;
  for (int i = tid; i < NPERS; i += 256) {
    s += (double)part[(size_t)i * 128 + o];
    q += (double)part[(size_t)i * 128 + 64 + o];
  }
  __shared__ double sd[256], qd[256];
  sd[tid] = s; qd[tid] = q;
  __syncthreads();
  for (int step = 128; step > 0; step >>= 1) {
    if (tid < step) { sd[tid] += sd[tid + step]; qd[tid] += qd[tid + step]; }
    __syncthreads();
  }
  if (tid == 0) {
    const double cnt = 480000.0;
    double mean = sd[0] / cnt;
    double var = qd[0] / cnt - mean * mean;
    float inv = rsqrtf((float)var + EPS_);
    float sc = gamma[o] * inv;
    float sh = beta[o] - (float)mean * sc;
    ss[2 * o] = sc;
    ss[2 * o + 1] = sh;
  }
}

// ---------------------------------------------------------------------------
// K3: recompute y (x L3-warm from k1), apply BN + residual + relu, store out.
// ---------------------------------------------------------------------------
__global__ __launch_bounds__(NTHR, 4) void k3_apply(
    const float* __restrict__ x, const float* __restrict__ A,
    const float* __restrict__ W, const float* __restrict__ b,
    const float* __restrict__ ss, float* __restrict__ out) {
  __shared__ __align__(16) SmemU sm;

  const int bid = blockIdx.x;
  const int tid = threadIdx.x;
  const int lane = tid & 63;
  const int wv = tid >> 6;
  const int ob = wv & 3;
  const int th = wv >> 2;
  const int l15 = lane & 15;
  const int lg = lane >> 4;

  stage_wa(A, W, sm, tid);
  __syncthreads();
  Frags F;
  read_frags(sm, b, ob, l15, lg, F);

  float sc[4], sh[4];
  #pragma unroll
  for (int r = 0; r < 4; ++r) {
    sc[r] = ss[2 * (F.obase + r)];
    sh[r] = ss[2 * (F.obase + r) + 1];
  }
  __syncthreads();                 // all wa reads done before xs overwrite

  #pragma unroll
  for (int i = 0; i < 2; ++i) {
    const int tile = bid * 2 + i;
    const int n = tile / NTILE;
    const int t0 = (tile - n * NTILE) * TT;

    stage_x(x, sm, n, t0, tid);
    __syncthreads();

    float* obp = out + (size_t)n * 480000 + (size_t)t0 * 25;

    #pragma unroll 2
    for (int tl = 0; tl < 6; ++tl) {
      const int t = th * 6 + tl;
      bf16x8 xf[4];
      #pragma unroll
      for (int q = 0; q < 4; ++q)
        xf[q] = *reinterpret_cast<const bf16x8*>(sm.xs + F.fK[q] + ((t << 5) ^ F.fS5[q]));
      #pragma unroll
      for (int wh = 0; wh < 2; ++wh) {
        f32x4 acc0, acc1;
        compute_wh(xf, F, wh, acc0, acc1);
        const int w = wh ? 16 + l15 : l15;
        if (w < V_) {
          #pragma unroll
          for (int r = 0; r < 4; ++r) {
            const int o = F.obase + r;
            float val = acc0[r] + acc1[r] + F.bs[r];
            float xr = (float)sm.xs[o * XROW + (((t << 5) + w) ^ emask(o))];
            obp[(size_t)o * 7500 + t * 25 + w] = fmaxf(sc[r] * val + sh[r] + xr, 0.f);
          }
        }
      }
    }
    __syncthreads();   // all xs reads done before next tile's stage_x
  }
}

extern "C" void kernel_launch(void* const* d_in, const int* in_sizes, int n_in,
                              void* d_out, int out_size, void* d_ws, size_t ws_size,
                              hipStream_t stream) {
  const float* x     = (const float*)d_in[0];
  const float* A     = (const float*)d_in[1];
  const float* W     = (const float*)d_in[2];
  const float* b     = (const float*)d_in[3];
  const float* gamma = (const float*)d_in[4];
  const float* beta  = (const float*)d_in[5];
  float* out = (float*)d_out;

  float* part = (float*)d_ws;                // NPERS*128 floats
  float* ss   = part + (size_t)NPERS * 128;  // 128 floats

  k1_stats<<<NPERS, NTHR, 0, stream>>>(x, A, W, b, part);
  k2_stats<<<64, 256, 0, stream>>>(part, gamma, beta, ss);
  k3_apply<<<NPERS, NTHR, 0, stream>>>(x, A, W, b, ss, out);
}

// Round 16
// 153.759 us; speedup vs baseline: 1.2797x; 1.0043x over previous
//
#include <hip/hip_runtime.h>
#include <hip/hip_bf16.h>

// Problem constants
#define N_ 64
#define C_ 64
#define T_ 300
#define V_ 25
#define K_ 3
#define TT 12             // t-values per tile
#define NTILE 25          // T_/TT
#define NBLK 1600         // total tiles
#define NPERS 800         // blocks; block bid owns tiles 2*bid, 2*bid+1
#define XROW 384          // xs row pitch in elems: TT*32
#define WP 72             // W-lds row pitch (144B, 16B-aligned b128 frag reads)
#define ATP 40            // At-lds row pitch (80B, 16B-aligned b128 frag reads)
#define NTHR 512          // 8 waves: (ob 0..3) x (t-half 0..1)
#define EPS_ 1e-5f

typedef __bf16 bf16_t;
typedef __bf16 bf16x4 __attribute__((ext_vector_type(4)));
typedef __bf16 bf16x8 __attribute__((ext_vector_type(8)));
typedef float f32x4 __attribute__((ext_vector_type(4)));
typedef float f32x4u __attribute__((ext_vector_type(4), aligned(4)));

static __device__ __forceinline__ bf16_t tobf(float f) { return (bf16_t)f; }
// element-index swizzle within a c-row (XOR of bits 3..5: keeps 4-runs contiguous)
static __device__ __forceinline__ int emask(int c) { return ((c & 3) << 3) | ((c & 8) << 2); }

// LDS overlay: W/A staging (prologue only; frags move to registers) reuses xs.
union SmemU {
  struct { bf16_t W[3 * 64 * WP]; bf16_t At[3 * 32 * ATP]; } wa;   // 35.3KB
  bf16_t xs[64 * XROW];                                            // 48KB
};

struct Frags {
  bf16x8 wfrag[6];
  bf16x8 afrag[3][2];
  int fK[4], fS5[4];
  float bs[4];
  int obase;
};

// ---- coalesced W/A global->LDS staging (bf16)
static __device__ __forceinline__ void stage_wa(
    const float* __restrict__ A, const float* __restrict__ W, SmemU& sm, int tid) {
  for (int m = tid; m < 3072; m += NTHR) {
    f32x4 v4 = *(reinterpret_cast<const f32x4*>(W) + m);
    int f = m << 2;
    int k = f >> 12, o = (f >> 6) & 63, c = f & 63;
    bf16x4 h;
    h[0] = tobf(v4[0]); h[1] = tobf(v4[1]); h[2] = tobf(v4[2]); h[3] = tobf(v4[3]);
    *reinterpret_cast<bf16x4*>(&sm.wa.W[(k * 64 + o) * WP + c]) = h;
  }
  for (int i = tid; i < 3072; i += NTHR) {
    int k = i >> 10, r = i & 1023, w = r >> 5, v = r & 31;
    float val = (v < V_ && w < V_) ? A[k * 625 + v * 25 + w] : 0.f;
    sm.wa.At[(k * 32 + w) * ATP + v] = tobf(val);
  }
}

static __device__ __forceinline__ void read_frags(
    const SmemU& sm, const float* __restrict__ b, int ob, int l15, int lg, Frags& F) {
  const int o = ob * 16 + l15;
  #pragma unroll
  for (int k = 0; k < 3; ++k)
    #pragma unroll
    for (int ch = 0; ch < 2; ++ch)
      F.wfrag[k * 2 + ch] =
          *reinterpret_cast<const bf16x8*>(&sm.wa.W[(k * 64 + o) * WP + ch * 32 + lg * 8]);
  #pragma unroll
  for (int k = 0; k < 3; ++k)
    #pragma unroll
    for (int wh = 0; wh < 2; ++wh)
      F.afrag[k][wh] =
          *reinterpret_cast<const bf16x8*>(&sm.wa.At[(k * 32 + wh * 16 + l15) * ATP + lg * 8]);
  // per-lane fragment LDS offsets. Permuted c-map (R3..R15-verified):
  // frag q=(chalf,sub): c = chalf*32 + sub*4 + 8*(l15>>2) + (l15&3)
  const int crow = 8 * (l15 >> 2) + (l15 & 3);
  #pragma unroll
  for (int q = 0; q < 4; ++q) {
    int c = ((q >> 1) * 32) + ((q & 1) * 4) + crow;
    int em = emask(c);
    F.fK[q] = c * XROW + ((lg * 8) ^ (em & 24));
    F.fS5[q] = em & 32;
  }
  F.obase = ob * 16 + lg * 4;
  #pragma unroll
  for (int r = 0; r < 4; ++r)
    F.bs[r] = b[F.obase + r] + b[64 + F.obase + r] + b[128 + F.obase + r];
}

// ---- overlapped touch: issue 3 line-strided loads of a FUTURE tile's x.
// Their only use (sink add) is placed after covering work, so the HBM
// latency hides. 1536 touches >= 1216 lines per tile. (R15: -20us measured)
static __device__ __forceinline__ void touch_issue(
    const float* __restrict__ x, int tile, int tid, float* tv) {
  const int n = tile / NTILE;
  const int t0 = (tile - n * NTILE) * TT;
  const float* base = x + (size_t)n * 480000 + (size_t)t0 * 25;
  #pragma unroll
  for (int j = 0; j < 3; ++j) {
    int idx = tid + (j << 9);          // 0..1535
    int c = idx / 19;                  // 19 lines (64B) per c-row
    int li = idx - c * 19;
    tv[j] = (c < 64) ? base[(size_t)c * 7500 + li * 16] : 0.f;
  }
}

// ---- x staging: 512 threads = 64 c-rows x 8 v-blocks; pure bit-op indexing.
static __device__ __forceinline__ void stage_x(
    const float* __restrict__ x, SmemU& sm, int n, int t0, int tid) {
  const int c = tid >> 3, vb = tid & 7;
  const int em = emask(c);
  const float* xr = x + (size_t)n * 480000 + (size_t)c * 7500 + (size_t)t0 * 25;
  bf16_t* xsr = &sm.xs[c * XROW];
  #pragma unroll
  for (int t = 0; t < TT; ++t) {
    bf16x4 h;
    if (vb < 6) {
      f32x4u v4 = *reinterpret_cast<const f32x4u*>(xr + t * 25 + vb * 4);
      h[0] = tobf(v4[0]); h[1] = tobf(v4[1]); h[2] = tobf(v4[2]); h[3] = tobf(v4[3]);
    } else if (vb == 6) {
      float s = xr[t * 25 + 24];
      h[0] = tobf(s); h[1] = tobf(0.f); h[2] = tobf(0.f); h[3] = tobf(0.f);
    } else {
      h[0] = tobf(0.f); h[1] = tobf(0.f); h[2] = tobf(0.f); h[3] = tobf(0.f);
    }
    *reinterpret_cast<bf16x4*>(&xsr[(((t << 5) + vb * 4) ^ em)]) = h;
  }
}

// one t, one wh: register-chained stage-A -> stage-B (R3..R15-verified mapping)
static __device__ __forceinline__ void compute_wh(
    const bf16x8* xf, const Frags& F, int wh, f32x4& acc0, f32x4& acc1) {
  acc0 = f32x4{0.f, 0.f, 0.f, 0.f};
  acc1 = f32x4{0.f, 0.f, 0.f, 0.f};
  #pragma unroll
  for (int k = 0; k < 3; ++k) {
    #pragma unroll
    for (int ch = 0; ch < 2; ++ch) {
      f32x4 zero = {0.f, 0.f, 0.f, 0.f};
      f32x4 dP = __builtin_amdgcn_mfma_f32_16x16x32_bf16(xf[ch * 2 + 0], F.afrag[k][wh], zero, 0, 0, 0);
      f32x4 dQ = __builtin_amdgcn_mfma_f32_16x16x32_bf16(xf[ch * 2 + 1], F.afrag[k][wh], zero, 0, 0, 0);
      bf16x8 zf;
      zf[0] = tobf(dP[0]); zf[1] = tobf(dP[1]); zf[2] = tobf(dP[2]); zf[3] = tobf(dP[3]);
      zf[4] = tobf(dQ[0]); zf[5] = tobf(dQ[1]); zf[6] = tobf(dQ[2]); zf[7] = tobf(dQ[3]);
      if (ch == 0)
        acc0 = __builtin_amdgcn_mfma_f32_16x16x32_bf16(F.wfrag[k * 2 + ch], zf, acc0, 0, 0, 0);
      else
        acc1 = __builtin_amdgcn_mfma_f32_16x16x32_bf16(F.wfrag[k * 2 + ch], zf, acc1, 0, 0, 0);
    }
  }
}

// ---------------------------------------------------------------------------
// K1: compute y (stored to d_out staging) + per-block channel partials.
// Tile 0's lines are pre-touched under the W/A prologue; tile 1's under
// tile-0's compute (both R15-validated overlapped-touch pattern).
// ---------------------------------------------------------------------------
__global__ __launch_bounds__(NTHR, 4) void k1_compute(
    const float* __restrict__ x, const float* __restrict__ A,
    const float* __restrict__ W, const float* __restrict__ b,
    float* __restrict__ y, float* __restrict__ part) {
  __shared__ __align__(16) SmemU sm;
  __shared__ float stats2[2][2][64];   // [sum|sq][t-half][o]

  const int bid = blockIdx.x;
  const int tid = threadIdx.x;
  const int lane = tid & 63;
  const int wv = tid >> 6;
  const int ob = wv & 3;
  const int th = wv >> 2;
  const int l15 = lane & 15;
  const int lg = lane >> 4;

  float sink = 0.f;
  {
    float tv0[3];
    touch_issue(x, bid * 2, tid, tv0);   // warm tile 0 under the prologue
    stage_wa(A, W, sm, tid);
    sink += tv0[0] + tv0[1] + tv0[2];    // consumed after prologue issue window
  }
  __syncthreads();
  Frags F;
  read_frags(sm, b, ob, l15, lg, F);
  __syncthreads();                 // all wa reads done before xs overwrite

  float lsum[4] = {0.f, 0.f, 0.f, 0.f}, lsq[4] = {0.f, 0.f, 0.f, 0.f};

  #pragma unroll
  for (int i = 0; i < 2; ++i) {
    const int tile = bid * 2 + i;
    const int n = tile / NTILE;
    const int t0 = (tile - n * NTILE) * TT;

    stage_x(x, sm, n, t0, tid);
    __syncthreads();

    float tv[3] = {0.f, 0.f, 0.f};
    if (i == 0) touch_issue(x, tile + 1, tid, tv);   // warm tile 1 under compute

    float* yb = y + (size_t)n * 480000 + (size_t)t0 * 25;

    #pragma unroll 2
    for (int tl = 0; tl < 6; ++tl) {
      const int t = th * 6 + tl;
      bf16x8 xf[4];
      #pragma unroll
      for (int q = 0; q < 4; ++q)
        xf[q] = *reinterpret_cast<const bf16x8*>(sm.xs + F.fK[q] + ((t << 5) ^ F.fS5[q]));
      #pragma unroll
      for (int wh = 0; wh < 2; ++wh) {
        f32x4 acc0, acc1;
        compute_wh(xf, F, wh, acc0, acc1);
        const int w = wh ? 16 + l15 : l15;
        if (w < V_) {
          #pragma unroll
          for (int r = 0; r < 4; ++r) {
            float val = acc0[r] + acc1[r] + F.bs[r];
            lsum[r] += val;
            lsq[r] += val * val;
            yb[(size_t)(F.obase + r) * 7500 + t * 25 + w] = val;
          }
        }
      }
    }
    sink += tv[0] + tv[1] + tv[2];   // touch consumption AFTER compute
    __syncthreads();   // all xs reads done before next tile's stage_x
  }
  asm volatile("" :: "v"(sink));     // keep touches alive (rule #17)

  #pragma unroll
  for (int d = 1; d < 16; d <<= 1) {
    #pragma unroll
    for (int r = 0; r < 4; ++r) {
      lsum[r] += __shfl_xor(lsum[r], d);
      lsq[r]  += __shfl_xor(lsq[r], d);
    }
  }
  if (l15 == 0) {
    #pragma unroll
    for (int r = 0; r < 4; ++r) {
      stats2[0][th][F.obase + r] = lsum[r];
      stats2[1][th][F.obase + r] = lsq[r];
    }
  }
  __syncthreads();
  if (tid < 128)
    part[(size_t)bid * 128 + tid] =
        stats2[tid >> 6][0][tid & 63] + stats2[tid >> 6][1][tid & 63];
}

// ---------------------------------------------------------------------------
// K2: reduce per-block partials -> per-channel scale/shift
// ---------------------------------------------------------------------------
__global__ __launch_bounds__(256) void k2_stats(
    const float* __restrict__ part,
    const float* __restrict__ gamma, const float* __restrict__ beta,
    float* __restrict__ ss) {
  const int o = blockIdx.x;
  const int tid = threadIdx.x;
  double s = 0.0, q = 0.0;
  for (int i = tid; i < NPERS; i += 256) {
    s += (double)part[(size_t)i * 128 + o];
    q += (double)part[(size_t)i * 128 + 64 + o];
  }
  __shared__ double sd[256], qd[256];
  sd[tid] = s; qd[tid] = q;
  __syncthreads();
  for (int step = 128; step > 0; step >>= 1) {
    if (tid < step) { sd[tid] += sd[tid + step]; qd[tid] += qd[tid + step]; }
    __syncthreads();
  }
  if (tid == 0) {
    const double cnt = 480000.0;
    double mean = sd[0] / cnt;
    double var = qd[0] / cnt - mean * mean;
    float inv = rsqrtf((float)var + EPS_);
    float sc = gamma[o] * inv;
    float sh = beta[o] - (float)mean * sc;
    ss[2 * o] = sc;
    ss[2 * o + 1] = sh;
  }
}

// ---------------------------------------------------------------------------
// K3: out = relu(scale[c]*y + shift[c] + x), in place on d_out (y staged
// there). One block per (n,c) plane; y and x both L3-resident (~9us measured).
// ---------------------------------------------------------------------------
__global__ __launch_bounds__(256) void k3_finish(
    const float* __restrict__ x, const float* __restrict__ ss,
    float* __restrict__ y) {
  const int p = blockIdx.x;       // 0..4095 = n*64 + c
  const int c = p & 63;
  const float sc = ss[2 * c];
  const float sh = ss[2 * c + 1];
  const float4* xv = reinterpret_cast<const float4*>(x + (size_t)p * 7500);
  float4* yv = reinterpret_cast<float4*>(y + (size_t)p * 7500);
  for (int i = threadIdx.x; i < 1875; i += 256) {
    float4 a = yv[i];
    float4 b4 = xv[i];
    float4 o;
    o.x = fmaxf(sc * a.x + sh + b4.x, 0.f);
    o.y = fmaxf(sc * a.y + sh + b4.y, 0.f);
    o.z = fmaxf(sc * a.z + sh + b4.z, 0.f);
    o.w = fmaxf(sc * a.w + sh + b4.w, 0.f);
    yv[i] = o;
  }
}

extern "C" void kernel_launch(void* const* d_in, const int* in_sizes, int n_in,
                              void* d_out, int out_size, void* d_ws, size_t ws_size,
                              hipStream_t stream) {
  const float* x     = (const float*)d_in[0];
  const float* A     = (const float*)d_in[1];
  const float* W     = (const float*)d_in[2];
  const float* b     = (const float*)d_in[3];
  const float* gamma = (const float*)d_in[4];
  const float* beta  = (const float*)d_in[5];
  float* y = (float*)d_out;                  // stage y in d_out, finish in place

  float* part = (float*)d_ws;                // NPERS*128 floats
  float* ss   = part + (size_t)NPERS * 128;  // 128 floats

  k1_compute<<<NPERS, NTHR, 0, stream>>>(x, A, W, b, y, part);
  k2_stats<<<64, 256, 0, stream>>>(part, gamma, beta, ss);
  k3_finish<<<4096, 256, 0, stream>>>(x, ss, y);
}

// Round 18
// 141.371 us; speedup vs baseline: 1.3918x; 1.0876x over previous
//
#include <hip/hip_runtime.h>
#include <hip/hip_bf16.h>

// Problem constants
#define N_ 64
#define C_ 64
#define T_ 300
#define V_ 25
#define K_ 3
#define TT 12             // t-values per tile
#define NTILE 25          // T_/TT
#define NBLK 1600         // total tiles
#define NPERS 800         // blocks; block bid owns tiles 2*bid, 2*bid+1
#define XROW 384          // xs row pitch in elems: TT*32
#define WP 72             // W-lds row pitch (144B, 16B-aligned b128 frag reads)
#define ATP 40            // At-lds row pitch (80B, 16B-aligned b128 frag reads)
#define NTHR 512          // 8 waves: (ob 0..3) x (t-half 0..1)
#define EPS_ 1e-5f

typedef __bf16 bf16_t;
typedef __bf16 bf16x4 __attribute__((ext_vector_type(4)));
typedef __bf16 bf16x8 __attribute__((ext_vector_type(8)));
typedef float f32x4 __attribute__((ext_vector_type(4)));
typedef float f32x4u __attribute__((ext_vector_type(4), aligned(4)));

static __device__ __forceinline__ bf16_t tobf(float f) { return (bf16_t)f; }
// element-index swizzle within a c-row (XOR of bits 3..5: keeps 4-runs contiguous)
static __device__ __forceinline__ int emask(int c) { return ((c & 3) << 3) | ((c & 8) << 2); }

// LDS overlay: W/A staging (prologue only; frags move to registers) reuses xs.
union SmemU {
  struct { bf16_t W[3 * 64 * WP]; bf16_t At[3 * 32 * ATP]; } wa;   // 35.3KB
  bf16_t xs[64 * XROW];                                            // 48KB
};

struct Frags {
  bf16x8 wfrag[6];
  bf16x8 afrag[3][2];
  int fK[4], fS5[4];
  float bs[4];
  int obase;
};

// ---- coalesced W/A global->LDS staging (bf16)
static __device__ __forceinline__ void stage_wa(
    const float* __restrict__ A, const float* __restrict__ W, SmemU& sm, int tid) {
  for (int m = tid; m < 3072; m += NTHR) {
    f32x4 v4 = *(reinterpret_cast<const f32x4*>(W) + m);
    int f = m << 2;
    int k = f >> 12, o = (f >> 6) & 63, c = f & 63;
    bf16x4 h;
    h[0] = tobf(v4[0]); h[1] = tobf(v4[1]); h[2] = tobf(v4[2]); h[3] = tobf(v4[3]);
    *reinterpret_cast<bf16x4*>(&sm.wa.W[(k * 64 + o) * WP + c]) = h;
  }
  for (int i = tid; i < 3072; i += NTHR) {
    int k = i >> 10, r = i & 1023, w = r >> 5, v = r & 31;
    float val = (v < V_ && w < V_) ? A[k * 625 + v * 25 + w] : 0.f;
    sm.wa.At[(k * 32 + w) * ATP + v] = tobf(val);
  }
}

static __device__ __forceinline__ void read_frags(
    const SmemU& sm, const float* __restrict__ b, int ob, int l15, int lg, Frags& F) {
  const int o = ob * 16 + l15;
  #pragma unroll
  for (int k = 0; k < 3; ++k)
    #pragma unroll
    for (int ch = 0; ch < 2; ++ch)
      F.wfrag[k * 2 + ch] =
          *reinterpret_cast<const bf16x8*>(&sm.wa.W[(k * 64 + o) * WP + ch * 32 + lg * 8]);
  #pragma unroll
  for (int k = 0; k < 3; ++k)
    #pragma unroll
    for (int wh = 0; wh < 2; ++wh)
      F.afrag[k][wh] =
          *reinterpret_cast<const bf16x8*>(&sm.wa.At[(k * 32 + wh * 16 + l15) * ATP + lg * 8]);
  // per-lane fragment LDS offsets. Permuted c-map (R3..R16-verified):
  // frag q=(chalf,sub): c = chalf*32 + sub*4 + 8*(l15>>2) + (l15&3)
  const int crow = 8 * (l15 >> 2) + (l15 & 3);
  #pragma unroll
  for (int q = 0; q < 4; ++q) {
    int c = ((q >> 1) * 32) + ((q & 1) * 4) + crow;
    int em = emask(c);
    F.fK[q] = c * XROW + ((lg * 8) ^ (em & 24));
    F.fS5[q] = em & 32;
  }
  F.obase = ob * 16 + lg * 4;
  #pragma unroll
  for (int r = 0; r < 4; ++r)
    F.bs[r] = b[F.obase + r] + b[64 + F.obase + r] + b[128 + F.obase + r];
}

// ---- overlapped touch: issue 3 line-strided loads of a FUTURE tile's x.
// Consumption (sink add) MUST sit after covering compute -- consuming before
// a barrier forces a vmcnt drain and serializes the HBM pull (R14/R16 bug).
static __device__ __forceinline__ void touch_issue(
    const float* __restrict__ x, int tile, int tid, float* tv) {
  const int n = tile / NTILE;
  const int t0 = (tile - n * NTILE) * TT;
  const float* base = x + (size_t)n * 480000 + (size_t)t0 * 25;
  #pragma unroll
  for (int j = 0; j < 3; ++j) {
    int idx = tid + (j << 9);          // 0..1535
    int c = idx / 19;                  // 19 lines (64B) per c-row
    int li = idx - c * 19;
    tv[j] = (c < 64) ? base[(size_t)c * 7500 + li * 16] : 0.f;
  }
}

// ---- x staging: 512 threads = 64 c-rows x 8 v-blocks; pure bit-op indexing.
static __device__ __forceinline__ void stage_x(
    const float* __restrict__ x, SmemU& sm, int n, int t0, int tid) {
  const int c = tid >> 3, vb = tid & 7;
  const int em = emask(c);
  const float* xr = x + (size_t)n * 480000 + (size_t)c * 7500 + (size_t)t0 * 25;
  bf16_t* xsr = &sm.xs[c * XROW];
  #pragma unroll
  for (int t = 0; t < TT; ++t) {
    bf16x4 h;
    if (vb < 6) {
      f32x4u v4 = *reinterpret_cast<const f32x4u*>(xr + t * 25 + vb * 4);
      h[0] = tobf(v4[0]); h[1] = tobf(v4[1]); h[2] = tobf(v4[2]); h[3] = tobf(v4[3]);
    } else if (vb == 6) {
      float s = xr[t * 25 + 24];
      h[0] = tobf(s); h[1] = tobf(0.f); h[2] = tobf(0.f); h[3] = tobf(0.f);
    } else {
      h[0] = tobf(0.f); h[1] = tobf(0.f); h[2] = tobf(0.f); h[3] = tobf(0.f);
    }
    *reinterpret_cast<bf16x4*>(&xsr[(((t << 5) + vb * 4) ^ em)]) = h;
  }
}

// one t, one wh: register-chained stage-A -> stage-B (R3..R16-verified mapping)
static __device__ __forceinline__ void compute_wh(
    const bf16x8* xf, const Frags& F, int wh, f32x4& acc0, f32x4& acc1) {
  acc0 = f32x4{0.f, 0.f, 0.f, 0.f};
  acc1 = f32x4{0.f, 0.f, 0.f, 0.f};
  #pragma unroll
  for (int k = 0; k < 3; ++k) {
    #pragma unroll
    for (int ch = 0; ch < 2; ++ch) {
      f32x4 zero = {0.f, 0.f, 0.f, 0.f};
      f32x4 dP = __builtin_amdgcn_mfma_f32_16x16x32_bf16(xf[ch * 2 + 0], F.afrag[k][wh], zero, 0, 0, 0);
      f32x4 dQ = __builtin_amdgcn_mfma_f32_16x16x32_bf16(xf[ch * 2 + 1], F.afrag[k][wh], zero, 0, 0, 0);
      bf16x8 zf;
      zf[0] = tobf(dP[0]); zf[1] = tobf(dP[1]); zf[2] = tobf(dP[2]); zf[3] = tobf(dP[3]);
      zf[4] = tobf(dQ[0]); zf[5] = tobf(dQ[1]); zf[6] = tobf(dQ[2]); zf[7] = tobf(dQ[3]);
      if (ch == 0)
        acc0 = __builtin_amdgcn_mfma_f32_16x16x32_bf16(F.wfrag[k * 2 + ch], zf, acc0, 0, 0, 0);
      else
        acc1 = __builtin_amdgcn_mfma_f32_16x16x32_bf16(F.wfrag[k * 2 + ch], zf, acc1, 0, 0, 0);
    }
  }
}

// ---------------------------------------------------------------------------
// K1: compute y (stored to d_out staging) + per-block channel partials.
// Tile 1's cache lines pulled by overlapped touches under tile-0's compute.
// NO prologue touch (R16 regression: pre-barrier sink = serialized HBM storm).
// ---------------------------------------------------------------------------
__global__ __launch_bounds__(NTHR, 4) void k1_compute(
    const float* __restrict__ x, const float* __restrict__ A,
    const float* __restrict__ W, const float* __restrict__ b,
    float* __restrict__ y, float* __restrict__ part) {
  __shared__ __align__(16) SmemU sm;
  __shared__ float stats2[2][2][64];   // [sum|sq][t-half][o]

  const int bid = blockIdx.x;
  const int tid = threadIdx.x;
  const int lane = tid & 63;
  const int wv = tid >> 6;
  const int ob = wv & 3;
  const int th = wv >> 2;
  const int l15 = lane & 15;
  const int lg = lane >> 4;

  stage_wa(A, W, sm, tid);
  __syncthreads();
  Frags F;
  read_frags(sm, b, ob, l15, lg, F);
  __syncthreads();                 // all wa reads done before xs overwrite

  float lsum[4] = {0.f, 0.f, 0.f, 0.f}, lsq[4] = {0.f, 0.f, 0.f, 0.f};
  float sink = 0.f;

  #pragma unroll
  for (int i = 0; i < 2; ++i) {
    const int tile = bid * 2 + i;
    const int n = tile / NTILE;
    const int t0 = (tile - n * NTILE) * TT;

    stage_x(x, sm, n, t0, tid);
    __syncthreads();

    float tv[3] = {0.f, 0.f, 0.f};
    if (i == 0) touch_issue(x, tile + 1, tid, tv);   // warm tile 1 under compute

    float* yb = y + (size_t)n * 480000 + (size_t)t0 * 25;

    #pragma unroll 2
    for (int tl = 0; tl < 6; ++tl) {
      const int t = th * 6 + tl;
      bf16x8 xf[4];
      #pragma unroll
      for (int q = 0; q < 4; ++q)
        xf[q] = *reinterpret_cast<const bf16x8*>(sm.xs + F.fK[q] + ((t << 5) ^ F.fS5[q]));
      #pragma unroll
      for (int wh = 0; wh < 2; ++wh) {
        f32x4 acc0, acc1;
        compute_wh(xf, F, wh, acc0, acc1);
        const int w = wh ? 16 + l15 : l15;
        if (w < V_) {
          #pragma unroll
          for (int r = 0; r < 4; ++r) {
            float val = acc0[r] + acc1[r] + F.bs[r];
            lsum[r] += val;
            lsq[r] += val * val;
            yb[(size_t)(F.obase + r) * 7500 + t * 25 + w] = val;
          }
        }
      }
    }
    sink += tv[0] + tv[1] + tv[2];   // touch consumption AFTER compute
    __syncthreads();   // all xs reads done before next tile's stage_x
  }
  asm volatile("" :: "v"(sink));     // keep touches alive (rule #17)

  #pragma unroll
  for (int d = 1; d < 16; d <<= 1) {
    #pragma unroll
    for (int r = 0; r < 4; ++r) {
      lsum[r] += __shfl_xor(lsum[r], d);
      lsq[r]  += __shfl_xor(lsq[r], d);
    }
  }
  if (l15 == 0) {
    #pragma unroll
    for (int r = 0; r < 4; ++r) {
      stats2[0][th][F.obase + r] = lsum[r];
      stats2[1][th][F.obase + r] = lsq[r];
    }
  }
  __syncthreads();
  if (tid < 128)
    part[(size_t)bid * 128 + tid] =
        stats2[tid >> 6][0][tid & 63] + stats2[tid >> 6][1][tid & 63];
}

// ---------------------------------------------------------------------------
// K2: reduce per-block partials -> per-channel scale/shift
// ---------------------------------------------------------------------------
__global__ __launch_bounds__(256) void k2_stats(
    const float* __restrict__ part,
    const float* __restrict__ gamma, const float* __restrict__ beta,
    float* __restrict__ ss) {
  const int o = blockIdx.x;
  const int tid = threadIdx.x;
  double s = 0.0, q = 0.0;
  for (int i = tid; i < NPERS; i += 256) {
    s += (double)part[(size_t)i * 128 + o];
    q += (double)part[(size_t)i * 128 + 64 + o];
  }
  __shared__ double sd[256], qd[256];
  sd[tid] = s; qd[tid] = q;
  __syncthreads();
  for (int step = 128; step > 0; step >>= 1) {
    if (tid < step) { sd[tid] += sd[tid + step]; qd[tid] += qd[tid + step]; }
    __syncthreads();
  }
  if (tid == 0) {
    const double cnt = 480000.0;
    double mean = sd[0] / cnt;
    double var = qd[0] / cnt - mean * mean;
    float inv = rsqrtf((float)var + EPS_);
    float sc = gamma[o] * inv;
    float sh = beta[o] - (float)mean * sc;
    ss[2 * o] = sc;
    ss[2 * o + 1] = sh;
  }
}

// ---------------------------------------------------------------------------
// K3: out = relu(scale[c]*y + shift[c] + x), in place on d_out (y staged
// there). Final stores NON-TEMPORAL via ext_vector f32x4 (clang builtin
// rejects HIP_vector_type float4 -- R17 compile fix): out is never re-read,
// keeping it out of L3 preserves x residency for the next replay's k1.
// ---------------------------------------------------------------------------
__global__ __launch_bounds__(256) void k3_finish(
    const float* __restrict__ x, const float* __restrict__ ss,
    float* __restrict__ y) {
  const int p = blockIdx.x;       // 0..4095 = n*64 + c
  const int c = p & 63;
  const float sc = ss[2 * c];
  const float sh = ss[2 * c + 1];
  const f32x4* xv = reinterpret_cast<const f32x4*>(x + (size_t)p * 7500);
  f32x4* yv = reinterpret_cast<f32x4*>(y + (size_t)p * 7500);
  for (int i = threadIdx.x; i < 1875; i += 256) {
    f32x4 a = yv[i];
    f32x4 b4 = xv[i];
    f32x4 o;
    o[0] = fmaxf(sc * a[0] + sh + b4[0], 0.f);
    o[1] = fmaxf(sc * a[1] + sh + b4[1], 0.f);
    o[2] = fmaxf(sc * a[2] + sh + b4[2], 0.f);
    o[3] = fmaxf(sc * a[3] + sh + b4[3], 0.f);
    __builtin_nontemporal_store(o, yv + i);
  }
}

extern "C" void kernel_launch(void* const* d_in, const int* in_sizes, int n_in,
                              void* d_out, int out_size, void* d_ws, size_t ws_size,
                              hipStream_t stream) {
  const float* x     = (const float*)d_in[0];
  const float* A     = (const float*)d_in[1];
  const float* W     = (const float*)d_in[2];
  const float* b     = (const float*)d_in[3];
  const float* gamma = (const float*)d_in[4];
  const float* beta  = (const float*)d_in[5];
  float* y = (float*)d_out;                  // stage y in d_out, finish in place

  float* part = (float*)d_ws;                // NPERS*128 floats
  float* ss   = part + (size_t)NPERS * 128;  // 128 floats

  k1_compute<<<NPERS, NTHR, 0, stream>>>(x, A, W, b, y, part);
  k2_stats<<<64, 256, 0, stream>>>(part, gamma, beta, ss);
  k3_finish<<<4096, 256, 0, stream>>>(x, ss, y);
}